// Round 2
// baseline (518.010 us; speedup 1.0000x reference)
//
#include <hip/hip_runtime.h>
#include <stdint.h>

// ---- problem constants ----
#define M_ROWS   224        // B*N = 32*7
#define K_DIM    49152      // D_MODEL*PATCH_NUMS
#define NCOL     1344       // 4 bands * 336
#define PRED     336
#define S_CHUNKS 24         // 21*24 = 504 blocks = 1.97/CU; halves P traffic vs 48
#define STEPS    64         // K-steps of 32 per chunk: 2048/32

// ws layout: P (bf16 partials, 14.5 MB) at 0. Xb pass eliminated (fused).

typedef __attribute__((ext_vector_type(8))) short short8;
typedef __attribute__((ext_vector_type(4))) float floatx4;

__device__ __forceinline__ uint16_t f32_to_bf16(float f) {
    uint32_t u = __builtin_bit_cast(uint32_t, f);
    uint32_t r = (u + 0x7fffu + ((u >> 16) & 1u)) >> 16;   // RNE
    return (uint16_t)r;
}
__device__ __forceinline__ float bf16_to_f32(uint16_t h) {
    uint32_t u = ((uint32_t)h) << 16;
    return __builtin_bit_cast(float, u);
}
__device__ __forceinline__ uint32_t pack2(float lo, float hi) {
    return (uint32_t)f32_to_bf16(lo) | ((uint32_t)f32_to_bf16(hi) << 16);
}

// ======================= Kernel 1: split-K GEMM, fused X-fp32->bf16 staging ====
// 504 blocks (1-D). Swizzle: id&7 ~ XCD (round-robin dispatch); all 21
// col-tiles of a K-chunk s land on one XCD -> the 1.83 MB fp32 A-chunk is
// read from HBM once per XCD and served 21x from its private L2 (per-step
// working set ~28 KB; 3 chunks/XCD). X conversion is fused via T14
// async reg-staging: issue fp32 loads after the barrier, MFMA on buf[cur],
// pack+ds_write into buf^1 after the MFMA phase. Per-lane LDS write addr
// == its afrag read addr, so the fragment layout is identical to the
// previous glds path.
__global__ __launch_bounds__(256, 2) void gemm_partial(
    const float* __restrict__ X,      // (224, 49152) fp32
    const float* __restrict__ W,      // (4, 49152, 336) fp32
    uint16_t* __restrict__ P)         // (224, 24, 1344) bf16 partials
{
    __shared__ uint16_t lA[2][14 * 512];     // 2 x 14 KB, fragment-ordered

    const int id = blockIdx.x;
    const int g  = id & 7;                   // presumed XCD
    const int q  = id >> 3;                  // 0..62
    const int ct = q % 21;                   // col-tile 0..20
    const int s  = g + 8 * (q / 21);         // K-chunk 0..23, s%8 == XCD

    const int tid  = threadIdx.x;
    const int lane = tid & 63;
    const int w    = tid >> 6;
    const int l15  = lane & 15;
    const int kq   = lane >> 4;
    const int c0w  = ct * 64 + w * 16;
    const int band = c0w / PRED;             // 16 | 336 -> no band straddle
    const int p0   = c0w - band * PRED;

    const float* wbase = W + (size_t)band * ((size_t)K_DIM * PRED)
                           + (size_t)(kq * 8) * PRED
                           + (size_t)(p0 + l15);
    const float* xbase = X + (size_t)l15 * K_DIM + (size_t)(kq * 8);
    const int kbase = s * (STEPS * 32);

    floatx4 acc[14];
    #pragma unroll
    for (int f = 0; f < 14; ++f) acc[f] = (floatx4){0.f, 0.f, 0.f, 0.f};

    float wcur[8], wnxt[8];
    float4 xr[4][2];                          // in-flight fp32 A slices (32 VGPR)

    // ---- prologue: X(0) + W(0); pack -> buf0 ----
    #pragma unroll
    for (int t = 0; t < 4; ++t) {
        const int f = w + 4 * t;
        if (f < 14) {
            const float* gp = xbase + (size_t)(16 * f) * K_DIM + kbase;
            xr[t][0] = *(const float4*)gp;
            xr[t][1] = *(const float4*)(gp + 4);
        }
    }
    #pragma unroll
    for (int j = 0; j < 8; ++j) wcur[j] = wbase[(size_t)(kbase + j) * PRED];
    #pragma unroll
    for (int t = 0; t < 4; ++t) {
        const int f = w + 4 * t;
        if (f < 14) {
            short8 v;
            ((uint32_t*)&v)[0] = pack2(xr[t][0].x, xr[t][0].y);
            ((uint32_t*)&v)[1] = pack2(xr[t][0].z, xr[t][0].w);
            ((uint32_t*)&v)[2] = pack2(xr[t][1].x, xr[t][1].y);
            ((uint32_t*)&v)[3] = pack2(xr[t][1].z, xr[t][1].w);
            *(short8*)&lA[0][f * 512 + lane * 8] = v;
        }
    }

    for (int st = 0; st < STEPS; ++st) {
        __syncthreads();   // drains ds_writes(st) + W(st); fences buf^1 reads
        const int cur = st & 1;

        if (st + 1 < STEPS) {
            const int kn = kbase + (st + 1) * 32;
            // T14 issue-early: fire the fp32 A loads for st+1 now; their
            // latency hides under the ds_read+MFMA phase below.
            #pragma unroll
            for (int t = 0; t < 4; ++t) {
                const int f = w + 4 * t;
                if (f < 14) {
                    const float* gp = xbase + (size_t)(16 * f) * K_DIM + kn;
                    xr[t][0] = *(const float4*)gp;
                    xr[t][1] = *(const float4*)(gp + 4);
                }
            }
            #pragma unroll
            for (int j = 0; j < 8; ++j) wnxt[j] = wbase[(size_t)(kn + j) * PRED];
        }

        short8 bfrag;
        #pragma unroll
        for (int j = 0; j < 4; ++j)
            ((uint32_t*)&bfrag)[j] = pack2(wcur[2 * j], wcur[2 * j + 1]);

        #pragma unroll
        for (int f = 0; f < 14; ++f) {
            short8 afrag = *(const short8*)&lA[cur][f * 512 + lane * 8];
            acc[f] = __builtin_amdgcn_mfma_f32_16x16x32_bf16(afrag, bfrag, acc[f], 0, 0, 0);
        }

        if (st + 1 < STEPS) {
            // T14 write-late: vmcnt waits for xr land here, after the MFMAs.
            #pragma unroll
            for (int t = 0; t < 4; ++t) {
                const int f = w + 4 * t;
                if (f < 14) {
                    short8 v;
                    ((uint32_t*)&v)[0] = pack2(xr[t][0].x, xr[t][0].y);
                    ((uint32_t*)&v)[1] = pack2(xr[t][0].z, xr[t][0].w);
                    ((uint32_t*)&v)[2] = pack2(xr[t][1].x, xr[t][1].y);
                    ((uint32_t*)&v)[3] = pack2(xr[t][1].z, xr[t][1].w);
                    *(short8*)&lA[cur ^ 1][f * 512 + lane * 8] = v;
                }
            }
            #pragma unroll
            for (int j = 0; j < 8; ++j) wcur[j] = wnxt[j];
        }
    }

    // ---- write bf16 partials: C/D layout col=lane&15, row=kq*4+reg ----
    const int col = c0w + l15;
    #pragma unroll
    for (int f = 0; f < 14; ++f) {
        #pragma unroll
        for (int r = 0; r < 4; ++r) {
            const int m = 16 * f + kq * 4 + r;
            P[((size_t)m * S_CHUNKS + s) * NCOL + col] = f32_to_bf16(acc[f][r]);
        }
    }
}

// ======================= Kernel 2: partial reduce + bias + iSWT =======================
__device__ const float REC_LO[8] = {
     0.23037781330885523f,  0.7148465705525415f,   0.6308807679295904f,
    -0.02798376941698385f, -0.18703481171888114f,  0.030841381835986965f,
     0.032883011666982945f, -0.010597401784997278f };
__device__ const float REC_HI[8] = {
     0.010597401784997278f, 0.032883011666982945f, -0.030841381835986965f,
    -0.18703481171888114f,  0.02798376941698385f,   0.6308807679295904f,
    -0.7148465705525415f,   0.23037781330885523f };

__global__ __launch_bounds__(1024) void reduce_iswt(
    const uint16_t* __restrict__ P,    // (224, 24, 1344) bf16
    const float* __restrict__ bias,    // (4, 336) flat == flat col
    float* __restrict__ out)           // (224, 336)
{
    __shared__ float coeff[NCOL];
    __shared__ float buf[2][PRED];

    const int row = blockIdx.x;
    const int tid = threadIdx.x;
    const uint32_t* pr = (const uint32_t*)(P + (size_t)row * S_CHUNKS * NCOL);

    if (tid < NCOL / 2) {
        float a0 = 0.f, a1 = 0.f;
        #pragma unroll 8
        for (int s = 0; s < S_CHUNKS; ++s) {
            const uint32_t v = pr[s * (NCOL / 2) + tid];
            a0 += bf16_to_f32((uint16_t)(v & 0xffff));
            a1 += bf16_to_f32((uint16_t)(v >> 16));
        }
        coeff[2 * tid]     = a0 + bias[2 * tid];
        coeff[2 * tid + 1] = a1 + bias[2 * tid + 1];
    }
    __syncthreads();

    if (tid < PRED) buf[0][tid] = coeff[tid];   // band 0 = cA
    __syncthreads();

    int curb = 0;
    for (int j = 3; j >= 1; --j) {
        const int step = 1 << (j - 1);              // 4, 2, 1
        const int M    = PRED / step;               // 84, 168, 336
        const float* cd  = &coeff[(4 - j) * PRED];  // cD3, cD2, cD1
        const float* cur = buf[curb];
        float* nxt       = buf[curb ^ 1];
        if (tid < PRED) {
            const int t = tid;
            const int sidx = t & (step - 1);
            const int m = t / step;
            const int mm1 = (m == 0) ? (M - 1) : (m - 1);
            float x1 = 0.f, x2 = 0.f;
            #pragma unroll
            for (int k = 0; k < 8; ++k) {
                int i1 = m + 3 - k;  if (i1 < 0) i1 += M; else if (i1 >= M) i1 -= M;
                if ((i1 & 1) == 0) {
                    const int pos = i1 * step + sidx;
                    x1 += cur[pos] * REC_LO[k] + cd[pos] * REC_HI[k];
                }
                int i2 = mm1 + 3 - k;  if (i2 < 0) i2 += M; else if (i2 >= M) i2 -= M;
                if ((i2 & 1) == 0) {
                    const int pos = (i2 + 1) * step + sidx;
                    x2 += cur[pos] * REC_LO[k] + cd[pos] * REC_HI[k];
                }
            }
            nxt[t] = 0.5f * (x1 + x2);
        }
        __syncthreads();
        curb ^= 1;
    }

    if (tid < PRED) out[(size_t)row * PRED + tid] = buf[curb][tid];
}

// ======================= launch =======================
extern "C" void kernel_launch(void* const* d_in, const int* in_sizes, int n_in,
                              void* d_out, int out_size, void* d_ws, size_t ws_size,
                              hipStream_t stream) {
    const float* X    = (const float*)d_in[0];   // (224, 49152)
    const float* W    = (const float*)d_in[1];   // (4, 49152, 336)
    const float* bias = (const float*)d_in[2];   // (4, 336)
    float* out        = (float*)d_out;           // (224, 336)
    uint16_t* P       = (uint16_t*)d_ws;         // 14.5 MB partials

    gemm_partial<<<21 * S_CHUNKS, 256, 0, stream>>>(X, W, P);
    reduce_iswt <<<M_ROWS, 1024, 0, stream>>>(P, bias, out);
}